// Round 3
// baseline (150.618 us; speedup 1.0000x reference)
//
#include <hip/hip_runtime.h>

#define NC 2048      // N_CLASSES
#define NB 65536     // BATCH
#define CAP 32       // max parents/children per class on the fast path

// ---------------- reduction helpers ----------------

__device__ inline float wred_sum(float v) {
#pragma unroll
    for (int o = 32; o > 0; o >>= 1) v += __shfl_xor(v, o);
    return v;
}

__device__ inline float wred_max(float v) {
#pragma unroll
    for (int o = 32; o > 0; o >>= 1) v = fmaxf(v, __shfl_xor(v, o));
    return v;
}

// ---------------- transpose H -> HT (2048x2048 f32) ----------------

__global__ __launch_bounds__(256) void hcl_transpose(const float* __restrict__ H,
                                                     float* __restrict__ HT) {
    __shared__ float tile[32][33];
    const int bx = blockIdx.x * 32, by = blockIdx.y * 32;
    const int tx = threadIdx.x, ty = threadIdx.y;  // 32 x 8
#pragma unroll
    for (int i = 0; i < 32; i += 8)
        tile[ty + i][tx] = H[(size_t)(by + ty + i) * NC + bx + tx];
    __syncthreads();
#pragma unroll
    for (int i = 0; i < 32; i += 8)
        HT[(size_t)(bx + ty + i) * NC + by + tx] = tile[tx][ty + i];
}

// ---------------- build per-class index lists (deterministic ballot compaction) ----
// One wave per row of M: idx[row*CAP + k] = k-th nonzero column (ascending),
// cnt[row] = exact nonzero count (may exceed CAP; entries beyond CAP dropped).

__global__ __launch_bounds__(256) void hcl_build(const float* __restrict__ M,
                                                 int* __restrict__ cnt,
                                                 int* __restrict__ idx) {
    const int row  = blockIdx.x * 4 + (threadIdx.x >> 6);
    const int lane = threadIdx.x & 63;
    int count = 0;
#pragma unroll
    for (int k = 0; k < NC / 64; ++k) {
        const int c = k * 64 + lane;
        const float v = M[(size_t)row * NC + c];
        const unsigned long long mask = __ballot(v != 0.0f);
        if (v != 0.0f) {
            const int pos = count + __popcll(mask & ((1ull << lane) - 1ull));
            if (pos < CAP) idx[row * CAP + pos] = c;
        }
        count += __popcll(mask);
    }
    if (lane == 0) cnt[row] = count;
}

// ---------------- main kernel: one wave per row, no LDS, no barriers ----------------

__global__ __launch_bounds__(256) void hcl_row3(
    const float* __restrict__ logits, const int* __restrict__ targets,
    const int* __restrict__ pcnt, const int* __restrict__ ccnt,
    const int* __restrict__ pidx, const int* __restrict__ cidx,
    const float* __restrict__ H,
    float* __restrict__ partial) {
    const int wid  = threadIdx.x >> 6;              // 0..3
    const int lane = threadIdx.x & 63;
    const int row  = blockIdx.x * 4 + wid;

    const float*  lrow  = logits + (size_t)row * NC;
    const float4* lrow4 = (const float4*)lrow;

    // stream the whole row into registers: 8 coalesced float4 loads in flight
    float4 v[8];
#pragma unroll
    for (int k = 0; k < 8; ++k) v[k] = lrow4[lane + 64 * k];

    float m = fmaxf(fmaxf(v[0].x, v[0].y), fmaxf(v[0].z, v[0].w));
#pragma unroll
    for (int k = 1; k < 8; ++k)
        m = fmaxf(m, fmaxf(fmaxf(v[k].x, v[k].y), fmaxf(v[k].z, v[k].w)));
    m = wred_max(m);

    float z = 0.f;
#pragma unroll
    for (int k = 0; k < 8; ++k)
        z += __expf(v[k].x - m) + __expf(v[k].y - m) +
             __expf(v[k].z - m) + __expf(v[k].w - m);
    const float Z = wred_sum(z);

    const int t  = targets[row];
    const int cp = pcnt[t], cc = ccnt[t];

    if (cp <= CAP && cc <= CAP) {
        // sparse gather: lanes 0-31 parents, lanes 32-63 children (L1-resident row)
        float acc = 0.f;
        if (lane < 32) {
            if (lane < cp) acc = __expf(lrow[pidx[t * CAP + lane]] - m);
        } else {
            if (lane - 32 < cc) acc = __expf(lrow[cidx[t * CAP + (lane - 32)]] - m);
        }
#pragma unroll
        for (int o = 16; o > 0; o >>= 1) acc += __shfl_xor(acc, o);
        const float PS = __shfl(acc, 0);
        const float CS = __shfl(acc, 32);
        if (lane == 0) {
            const float xt = lrow[t];
            const float pt = __expf(xt - m) / Z;
            const float ce = logf(Z) + (m - xt);     // -log p_t
            float h = 0.f;
            if (cp > 0) h += fmaxf(pt - PS / Z, 0.f);
            if (cc > 0) h += fmaxf(CS / Z - pt, 0.f);
            partial[row] = ce + h;                    // ALPHA = 1
        }
    } else {
        // dense in-wave fallback (never taken for this data; safety net)
        const float4* hr4 = (const float4*)(H + (size_t)t * NC);
        float cs = 0.f, ps = 0.f;
#pragma unroll
        for (int k = 0; k < 8; ++k) {
            const float4 h4 = hr4[lane + 64 * k];
            const float e0 = __expf(v[k].x - m), e1 = __expf(v[k].y - m);
            const float e2 = __expf(v[k].z - m), e3 = __expf(v[k].w - m);
            cs += e0 * h4.x + e1 * h4.y + e2 * h4.z + e3 * h4.w;
            const size_t c0 = 4 * (size_t)(lane + 64 * k);
            ps += e0 * H[(c0 + 0) * NC + t] + e1 * H[(c0 + 1) * NC + t] +
                  e2 * H[(c0 + 2) * NC + t] + e3 * H[(c0 + 3) * NC + t];
        }
        const float CS = wred_sum(cs);
        const float PS = wred_sum(ps);
        if (lane == 0) {
            const float xt = lrow[t];
            const float pt = __expf(xt - m) / Z;
            const float ce = logf(Z) + (m - xt);
            float h = 0.f;
            if (cp > 0) h += fmaxf(pt - PS / Z, 0.f);
            if (cc > 0) h += fmaxf(CS / Z - pt, 0.f);
            partial[row] = ce + h;
        }
    }
}

// ---------------- legacy fallback row kernel (small-ws paths) ----------------

template <int MODE>  // 1: write partials; 2: atomic into out
__global__ __launch_bounds__(256) void hcl_row_kernel(
    const float* __restrict__ logits, const int* __restrict__ targets,
    const float* __restrict__ H, float* __restrict__ partial, float* __restrict__ out) {
    const int wid  = threadIdx.x >> 6;
    const int lane = threadIdx.x & 63;
    const int row  = blockIdx.x * 4 + wid;

    const float*  lrow  = logits + (size_t)row * NC;
    const float4* lrow4 = (const float4*)lrow;
    float4 v[8];
#pragma unroll
    for (int k = 0; k < 8; ++k) v[k] = lrow4[lane + 64 * k];
    const int t = targets[row];

    float m = fmaxf(fmaxf(v[0].x, v[0].y), fmaxf(v[0].z, v[0].w));
#pragma unroll
    for (int k = 1; k < 8; ++k)
        m = fmaxf(m, fmaxf(fmaxf(v[k].x, v[k].y), fmaxf(v[k].z, v[k].w)));
    m = wred_max(m);

    float z = 0.f;
#pragma unroll
    for (int k = 0; k < 8; ++k)
        z += __expf(v[k].x - m) + __expf(v[k].y - m) +
             __expf(v[k].z - m) + __expf(v[k].w - m);
    const float Z = wred_sum(z);

    const float4* hr4 = (const float4*)(H + (size_t)t * NC);
    float cs = 0.f, hcs = 0.f, ps = 0.f, hps = 0.f;
#pragma unroll
    for (int k = 0; k < 8; ++k) {
        const float4 h4 = hr4[lane + 64 * k];
        const float e0 = __expf(v[k].x - m), e1 = __expf(v[k].y - m);
        const float e2 = __expf(v[k].z - m), e3 = __expf(v[k].w - m);
        cs  += e0 * h4.x + e1 * h4.y + e2 * h4.z + e3 * h4.w;
        hcs += h4.x + h4.y + h4.z + h4.w;
        const size_t c0 = 4 * (size_t)(lane + 64 * k);
        const float p0 = H[(c0 + 0) * NC + t], p1 = H[(c0 + 1) * NC + t];
        const float p2 = H[(c0 + 2) * NC + t], p3 = H[(c0 + 3) * NC + t];
        ps  += e0 * p0 + e1 * p1 + e2 * p2 + e3 * p3;
        hps += p0 + p1 + p2 + p3;
    }
    const float CS  = wred_sum(cs);
    const float HCS = wred_sum(hcs);
    const float PS  = wred_sum(ps);
    const float HPS = wred_sum(hps);

    if (lane == 0) {
        const float xt = lrow[t];
        const float pt = __expf(xt - m) / Z;
        const float ce = logf(Z) + (m - xt);
        float h = 0.f;
        if (HPS > 0.f) h += fmaxf(pt - PS / Z, 0.f);
        if (HCS > 0.f) h += fmaxf(CS / Z - pt, 0.f);
        const float val = ce + h;
        if (MODE == 2) atomicAdd(out, val * (1.0f / NB));
        else           partial[row] = val;
    }
}

// ---------------- final reduction (single block, deterministic) ----------------

__global__ __launch_bounds__(1024) void hcl_final_single(const float* __restrict__ partial,
                                                         float* __restrict__ out) {
    __shared__ double sm[16];
    double acc = 0.0;
    for (int i = threadIdx.x; i < NB; i += 1024) acc += (double)partial[i];
#pragma unroll
    for (int o = 32; o > 0; o >>= 1) acc += __shfl_xor(acc, o);
    const int wid = threadIdx.x >> 6, lane = threadIdx.x & 63;
    if (lane == 0) sm[wid] = acc;
    __syncthreads();
    if (threadIdx.x == 0) {
        double s = 0.0;
        for (int i = 0; i < 16; i++) s += sm[i];
        out[0] = (float)(s / (double)NB);
    }
}

// ---------------- launch ----------------

extern "C" void kernel_launch(void* const* d_in, const int* in_sizes, int n_in,
                              void* d_out, int out_size, void* d_ws, size_t ws_size,
                              hipStream_t stream) {
    const float* logits  = (const float*)d_in[0];
    const int*   targets = (const int*)d_in[1];
    const float* H       = (const float*)d_in[2];
    float* out = (float*)d_out;

    // fast-path workspace layout
    size_t off = 0;
    float* HT      = (float*)d_ws;                 off += (size_t)NC * NC * 4;  // 16 MB
    float* partial = (float*)((char*)d_ws + off);  off += (size_t)NB * 4;       // 256 KB
    int*   pcnt    = (int*)((char*)d_ws + off);    off += NC * 4;
    int*   ccnt    = (int*)((char*)d_ws + off);    off += NC * 4;
    int*   pidx    = (int*)((char*)d_ws + off);    off += (size_t)NC * CAP * 4;
    int*   cidx    = (int*)((char*)d_ws + off);    off += (size_t)NC * CAP * 4;
    const size_t NEED_FAST = off;
    const size_t NEED_PART = (size_t)NB * sizeof(float);

    if (ws_size >= NEED_FAST) {
        hcl_transpose<<<dim3(64, 64), dim3(32, 8), 0, stream>>>(H, HT);
        hcl_build<<<NC / 4, 256, 0, stream>>>(H,  ccnt, cidx);   // children(r): nonzero cols of row r
        hcl_build<<<NC / 4, 256, 0, stream>>>(HT, pcnt, pidx);   // parents(c):  nonzero rows of col c
        hcl_row3<<<NB / 4, 256, 0, stream>>>(logits, targets, pcnt, ccnt, pidx, cidx, H, partial);
        hcl_final_single<<<1, 1024, 0, stream>>>(partial, out);
    } else if (ws_size >= NEED_PART) {
        float* part = (float*)d_ws;
        hcl_row_kernel<1><<<NB / 4, 256, 0, stream>>>(logits, targets, H, part, out);
        hcl_final_single<<<1, 1024, 0, stream>>>(part, out);
    } else {
        hipMemsetAsync(d_out, 0, sizeof(float), stream);
        hcl_row_kernel<2><<<NB / 4, 256, 0, stream>>>(logits, targets, H, nullptr, out);
    }
}